// Round 3
// baseline (784.810 us; speedup 1.0000x reference)
//
#include <hip/hip_runtime.h>
#include <math.h>

#define DD 2048
#define EE 64
#define TOK_TILE 256
#define KSPLIT 4
#define KRANGE (DD / KSPLIT)   // 512
#define BK 32
#define NCH (KRANGE / BK)      // 16
#define THREADS 256

// GEMM with 4-way split-K. Tile: 256 tokens x 64 experts, 8x8 acc/thread.
// LDS: x double-buffered (64 KB) + W single-buffered (8 KB) = 72 KB -> 2 blocks/CU.
// All staging via global_load_lds(16B) with XOR-swizzled source quads; compute
// reads are 8-lane broadcasts over 8 distinct bank-quads -> conflict-free.
template<int ATOMIC>
__global__ __launch_bounds__(THREADS, 2) void gemm_kernel(
    const float* __restrict__ x, const float* __restrict__ W,
    float* __restrict__ partial, int n_tokens)
{
    __shared__ __align__(16) float xs[2][TOK_TILE * BK];
    __shared__ __align__(16) float wsh[EE * BK];

    const int tid  = threadIdx.x;
    const int wv   = tid >> 6;    // wave 0..3
    const int lane = tid & 63;
    const int tx   = tid & 7;     // experts {tx + 8j}, j<8
    const int ty   = tid >> 3;    // tokens  {ty + 32i}, i<8   (ty 0..31)
    const int tileId = blockIdx.x >> 2;
    const int ks     = blockIdx.x & 3;
    const int tBase  = tileId * TOK_TILE;

    const float* xg = x + (size_t)tBase * DD + ks * KRANGE;
    const float* Wg = W + ks * KRANGE;

    const int rl = lane >> 3;   // row within 8-row staging group
    const int pq = lane & 7;    // physical quad (LDS dest = base + lane*16)
    const int sq = pq ^ rl;     // swizzled source quad: phys q holds logical q^(row&7)

    float acc[8][8];
#pragma unroll
    for (int i = 0; i < 8; ++i)
#pragma unroll
        for (int j = 0; j < 8; ++j) acc[i][j] = 0.f;

    auto stage_x = [&](int buf, int c) {
#pragma unroll
        for (int i = 0; i < 8; ++i) {
            const int rowg = 64 * wv + 8 * i;                 // 8-row group base
            const float* src = xg + (size_t)(rowg + rl) * DD + c * BK + 4 * sq;
            __builtin_amdgcn_global_load_lds(
                (const __attribute__((address_space(1))) void*)src,
                (__attribute__((address_space(3))) void*)&xs[buf][rowg * BK],
                16, 0, 0);
        }
    };
    auto stage_w = [&](int c) {
#pragma unroll
        for (int i = 0; i < 2; ++i) {
            const int rowg = 16 * wv + 8 * i;
            const float* src = Wg + (size_t)(rowg + rl) * DD + c * BK + 4 * sq;
            __builtin_amdgcn_global_load_lds(
                (const __attribute__((address_space(1))) void*)src,
                (__attribute__((address_space(3))) void*)&wsh[rowg * BK],
                16, 0, 0);
        }
    };

    auto compute = [&](int buf) {
#pragma unroll
        for (int k4 = 0; k4 < BK / 4; ++k4) {
            float4 xv[8], wv4[8];
#pragma unroll
            for (int i = 0; i < 8; ++i)   // 8-lane broadcast, 8 distinct quads: conflict-free
                xv[i] = *(const float4*)&xs[buf][(ty + 32 * i) * BK + 4 * (k4 ^ (ty & 7))];
#pragma unroll
            for (int j = 0; j < 8; ++j)   // same
                wv4[j] = *(const float4*)&wsh[(tx + 8 * j) * BK + 4 * (k4 ^ tx)];
#pragma unroll
            for (int i = 0; i < 8; ++i)
#pragma unroll
                for (int j = 0; j < 8; ++j) {
                    acc[i][j] += xv[i].x * wv4[j].x;
                    acc[i][j] += xv[i].y * wv4[j].y;
                    acc[i][j] += xv[i].z * wv4[j].z;
                    acc[i][j] += xv[i].w * wv4[j].w;
                }
        }
    };

    // Pipeline: issue order per iter is [x(c+1):8][then, post-compute, W(c+1):2].
    // At the vmcnt(8) wait, the 8 newest (x of next chunk) may stay in flight;
    // everything older (x(c) and W(c)) is guaranteed landed.
    stage_x(0, 0);
    stage_w(0);
    int buf = 0;
#pragma unroll 1
    for (int c = 0; c < NCH; ++c) {
        if (c + 1 < NCH) {
            stage_x(buf ^ 1, c + 1);
            asm volatile("s_waitcnt vmcnt(8)\n\ts_barrier" ::: "memory");
        } else {
            asm volatile("s_waitcnt vmcnt(0)\n\ts_barrier" ::: "memory");
        }
        compute(buf);
        asm volatile("s_waitcnt lgkmcnt(0)\n\ts_barrier" ::: "memory");
        if (c + 1 < NCH) stage_w(c + 1);   // wsh reads drained by the barrier above
        buf ^= 1;
    }

    if (ATOMIC) {
#pragma unroll
        for (int i = 0; i < 8; ++i)
#pragma unroll
            for (int j = 0; j < 8; ++j)
                atomicAdd(&partial[(size_t)(tBase + ty + 32 * i) * EE + tx + 8 * j],
                          acc[i][j]);
    } else {
        float* dst = partial + ((size_t)ks * n_tokens + tBase) * EE;
#pragma unroll
        for (int i = 0; i < 8; ++i)
#pragma unroll
            for (int j = 0; j < 8; ++j)
                dst[(ty + 32 * i) * EE + tx + 8 * j] = acc[i][j];
    }
}

__global__ __launch_bounds__(256) void topk_kernel(
    const float* __restrict__ partial, const float* __restrict__ bias,
    float* __restrict__ out, int n_tokens, int nparts)
{
    const int t = blockIdx.x * 256 + threadIdx.x;
    if (t >= n_tokens) return;

    float lg[EE];
#pragma unroll
    for (int e = 0; e < EE; ++e) lg[e] = bias[e];

    for (int ksp = 0; ksp < nparts; ++ksp) {   // fixed order: deterministic sum
        const float4* pr = (const float4*)(partial + ((size_t)ksp * n_tokens + t) * EE);
#pragma unroll
        for (int q = 0; q < EE / 4; ++q) {
            const float4 v = pr[q];
            lg[4 * q + 0] += v.x; lg[4 * q + 1] += v.y;
            lg[4 * q + 2] += v.z; lg[4 * q + 3] += v.w;
        }
    }

    float v1 = -INFINITY, v2 = -INFINITY;
    int   i1 = 0, i2 = 0;
#pragma unroll
    for (int e = 0; e < EE; ++e) {
        const float v = lg[e];
        if (v > v1) { v2 = v1; i2 = i1; v1 = v; i1 = e; }
        else if (v > v2) { v2 = v; i2 = e; }
    }
    const float ed  = expf(v2 - v1);
    const float inv = 1.f / (1.f + ed);
    out[t * 2 + 0] = inv;
    out[t * 2 + 1] = ed * inv;
    float* oidx = out + (size_t)2 * n_tokens;
    oidx[t * 2 + 0] = (float)i1;
    oidx[t * 2 + 1] = (float)i2;
}

extern "C" void kernel_launch(void* const* d_in, const int* in_sizes, int n_in,
                              void* d_out, int out_size, void* d_ws, size_t ws_size,
                              hipStream_t stream) {
    const float* x = (const float*)d_in[0];
    const float* W = (const float*)d_in[1];
    const float* b = (const float*)d_in[2];
    float* out = (float*)d_out;

    const int n_tokens = in_sizes[0] / DD;            // 16384
    const int n_blocks = (n_tokens / TOK_TILE) * KSPLIT;  // 256
    const int tk_blocks = (n_tokens + 255) / 256;

    const size_t det_bytes = (size_t)KSPLIT * n_tokens * EE * sizeof(float);  // 16 MB
    float* part = (float*)d_ws;

    if (ws_size >= det_bytes) {
        gemm_kernel<0><<<n_blocks, THREADS, 0, stream>>>(x, W, part, n_tokens);
        topk_kernel<<<tk_blocks, 256, 0, stream>>>(part, b, out, n_tokens, KSPLIT);
    } else {
        hipMemsetAsync(d_ws, 0, (size_t)n_tokens * EE * sizeof(float), stream);
        gemm_kernel<1><<<n_blocks, THREADS, 0, stream>>>(x, W, part, n_tokens);
        topk_kernel<<<tk_blocks, 256, 0, stream>>>(part, b, out, n_tokens, 1);
    }
}

// Round 4
// 513.383 us; speedup vs baseline: 1.5287x; 1.5287x over previous
//
#include <hip/hip_runtime.h>
#include <math.h>

#define DD 2048
#define EE 64
#define TPB 512
#define NW 8             // waves per block, in-block split-K
#define KR (DD / NW)     // 256 k per wave
#define BK 32            // k per chunk
#define NCH (KR / BK)    // 8 chunks
#define LSTR 65          // logits stride: bank=(tok+e)%32 -> 2-way, free
#define RSZ (2 * 64 * BK)  // per-wave staging region, floats (2 bufs x 64 tok x 32 k)

// Block = 64 tokens (lane <-> token), 8 waves split K. acc[64] per thread in
// VGPRs. W is read with wave-uniform addresses -> s_load + scalar-operand FMA:
// zero LDS traffic for W, 1 ds_read_b128 per 256 FMAs for x.
// Staging: wave-private double-buffered global_load_lds(16B), per-wave vmcnt
// waits, NO barriers in the main loop. XOR quad swizzle (phys q = log q ^ (row&7))
// keeps DMA layout contiguous and compute reads conflict-free.
__global__ __launch_bounds__(TPB, 1) void router_kernel(
    const float* __restrict__ x, const float* __restrict__ W,
    const float* __restrict__ bias_g, float* __restrict__ out, int n_tokens)
{
    __shared__ __align__(16) float xs[NW][RSZ];      // 128 KB
    __shared__ float logits[64 * LSTR];              // 16.6 KB

    const int tid   = threadIdx.x;
    const int lane  = tid & 63;
    const int wvu   = __builtin_amdgcn_readfirstlane(tid >> 6);  // provably uniform
    const int tBase = blockIdx.x * 64;

    const float* xg = x + (size_t)tBase * DD + wvu * KR;
    const float* Wg = W + wvu * KR;   // uniform pointer

    float acc[EE];
#pragma unroll
    for (int e = 0; e < EE; ++e) acc[e] = 0.f;

    const int rg = lane >> 3;          // row within 8-row staging group
    const int sq = (lane & 7) ^ rg;    // source logical quad for phys quad (lane&7)

    auto stage = [&](int buf, int c) {
#pragma unroll
        for (int i = 0; i < 8; ++i) {  // 8 instrs: 64 rows x 128 B per chunk
            const float* src = xg + (size_t)(8 * i + rg) * DD + c * BK + 4 * sq;
            __builtin_amdgcn_global_load_lds(
                (const __attribute__((address_space(1))) void*)src,
                (__attribute__((address_space(3))) void*)
                    &xs[wvu][buf * (64 * BK) + 8 * i * BK],
                16, 0, 0);
        }
    };

    stage(0, 0);
    const int swz = lane & 7;
#pragma unroll 1
    for (int c = 0; c < NCH; ++c) {
        const int buf = c & 1;
        if (c + 1 < NCH) {
            stage(buf ^ 1, c + 1);
            asm volatile("s_waitcnt vmcnt(8)" ::: "memory");  // chunk c landed
        } else {
            asm volatile("s_waitcnt vmcnt(0)" ::: "memory");
        }
        const float* xrow = &xs[wvu][buf * (64 * BK) + lane * BK];
#pragma unroll 2
        for (int k4 = 0; k4 < BK / 4; ++k4) {
            const float4 xv = *(const float4*)&xrow[4 * (k4 ^ swz)];
            const int kk = c * BK + 4 * k4;   // uniform
#pragma unroll
            for (int e = 0; e < EE; ++e) {
                const float4 wv = *(const float4*)&Wg[(size_t)e * DD + kk]; // s_load
                acc[e] += xv.x * wv.x + xv.y * wv.y + xv.z * wv.z + xv.w * wv.w;
            }
        }
    }

    // ---- write this wave's 64x64 partial into its own (now free) region ----
    // layout [tok][64 exp], logical quad e4 stored at phys quad e4 ^ (tok&15)
    const int qsw = lane & 15;
#pragma unroll
    for (int e4 = 0; e4 < 16; ++e4) {
        float4 v;
        v.x = acc[4 * e4 + 0]; v.y = acc[4 * e4 + 1];
        v.z = acc[4 * e4 + 2]; v.w = acc[4 * e4 + 3];
        *(float4*)&xs[wvu][lane * 64 + 4 * (e4 ^ qsw)] = v;
    }
    __syncthreads();

    // ---- deterministic cross-wave reduction: thread (tok, eb) sums 8 waves ----
    {
        const int tok = tid & 63;
        const int eb  = tid >> 6;         // expert block: experts 8*eb .. 8*eb+7
        const int m   = tok & 15;
        float s[8];
#pragma unroll
        for (int k = 0; k < 8; ++k) s[k] = bias_g[8 * eb + k];
#pragma unroll
        for (int w = 0; w < NW; ++w) {    // fixed order: deterministic
            const float* r = &xs[w][tok * 64];
            const float4 a = *(const float4*)&r[4 * ((2 * eb + 0) ^ m)];
            const float4 b = *(const float4*)&r[4 * ((2 * eb + 1) ^ m)];
            s[0] += a.x; s[1] += a.y; s[2] += a.z; s[3] += a.w;
            s[4] += b.x; s[5] += b.y; s[6] += b.z; s[7] += b.w;
        }
#pragma unroll
        for (int k = 0; k < 8; ++k) logits[tok * LSTR + 8 * eb + k] = s[k];
    }
    __syncthreads();

    // ---- top-2 + softmax, one thread per token ----
    if (tid < 64) {
        const float* lrow = &logits[tid * LSTR];
        float v1 = -INFINITY, v2 = -INFINITY;
        int   i1 = 0, i2 = 0;
        for (int e = 0; e < EE; ++e) {
            const float v = lrow[e];
            if (v > v1) { v2 = v1; i2 = i1; v1 = v; i1 = e; }
            else if (v > v2) { v2 = v; i2 = e; }
        }
        const float ed  = expf(v2 - v1);
        const float inv = 1.f / (1.f + ed);
        const int tok = tBase + tid;
        out[tok * 2 + 0] = inv;
        out[tok * 2 + 1] = ed * inv;
        float* oidx = out + (size_t)2 * n_tokens;
        oidx[tok * 2 + 0] = (float)i1;
        oidx[tok * 2 + 1] = (float)i2;
    }
}

extern "C" void kernel_launch(void* const* d_in, const int* in_sizes, int n_in,
                              void* d_out, int out_size, void* d_ws, size_t ws_size,
                              hipStream_t stream) {
    const float* x = (const float*)d_in[0];
    const float* W = (const float*)d_in[1];
    const float* b = (const float*)d_in[2];
    float* out = (float*)d_out;

    const int n_tokens = in_sizes[0] / DD;  // 16384
    const int n_blocks = n_tokens / 64;     // 256 -> 1 block/CU

    router_kernel<<<n_blocks, TPB, 0, stream>>>(x, W, b, out, n_tokens);
}

// Round 5
// 296.817 us; speedup vs baseline: 2.6441x; 1.7296x over previous
//
#include <hip/hip_runtime.h>
#include <math.h>

#define DD 2048
#define EE 64
#define TPB 256
#define NW 4             // waves per block, in-block K-split
#define KR (DD / NW)     // 512 k per wave
#define BK 32            // k per staged chunk
#define NCH (KR / BK)    // 16
#define GS 260           // LDS group stride (8 rows * BK + 4 pad floats)
#define XREG (8 * GS)    // 2080 floats per x buffer
#define PSTR 68          // partial-logits row stride (pad +4)
#define WPS 2080         // padded W row stride in workspace (breaks L1 set aliasing)

// Re-stride W [64][2048] -> Wp [64][2080] so expert rows don't alias L1 sets.
__global__ __launch_bounds__(256) void wprep_kernel(
    const float* __restrict__ W, float* __restrict__ Wp)
{
    const int e = blockIdx.x;
    const int t = threadIdx.x;
    const float4* s = (const float4*)(W + (size_t)e * DD);
    float4* d = (float4*)(Wp + (size_t)e * WPS);
    d[t] = s[t];
    d[t + 256] = s[t + 256];
}

// 64 tok x 64 exp per block, 4 waves split K (512 each), 8x8 acc per thread.
// x: per-wave double-buffered LDS via global_load_lds, group-padded + XOR-group
//    addressing -> conflict-free b128 reads, no barriers in the main loop.
// W: direct global b128 reads along k (padded stride), L1-resident slice.
__global__ __launch_bounds__(TPB, 1) void router_kernel(
    const float* __restrict__ x, const float* __restrict__ Wg, const int wstride,
    const float* __restrict__ bias_g, float* __restrict__ out, const int n_tokens)
{
    __shared__ __align__(16) float xs[NW * 2 * XREG];     // 66.6 KB
    __shared__ __align__(16) float part[NW * 64 * PSTR];  // 69.6 KB

    const int tid   = threadIdx.x;
    const int lane  = tid & 63;
    const int wvu   = tid >> 6;   // wave 0..3 -> k range [512*wvu, 512*wvu+512)
    const int ty    = lane >> 3;  // token row-in-group; tokens {8*(j^ty)+ty}
    const int tx    = lane & 7;   // expert row-in-group; experts {8*(h^tx)+tx}
    const int tBase = blockIdx.x * 64;

    const float* xg = x + (size_t)tBase * DD + wvu * KR;
    const float* wk = Wg + wvu * KR;
    float* myxs = &xs[wvu * 2 * XREG];

    const int srow  = lane >> 3;  // staging: row in group
    const int squad = lane & 7;   // staging: 16B quad in row

    int woff[8];                  // per-slot W row offsets (floats), computed once
#pragma unroll
    for (int h = 0; h < 8; ++h)
        woff[h] = (8 * (h ^ tx) + tx) * wstride;

    float acc[8][8];
#pragma unroll
    for (int j = 0; j < 8; ++j)
#pragma unroll
        for (int h = 0; h < 8; ++h) acc[j][h] = 0.f;

#define STAGE(buf, c)                                                         \
    {                                                                         \
        const float* sb_ = xg + (c) * BK + 4 * squad;                         \
        _Pragma("unroll")                                                     \
        for (int i_ = 0; i_ < 8; ++i_) {                                      \
            __builtin_amdgcn_global_load_lds(                                 \
                (const __attribute__((address_space(1))) void*)               \
                    (sb_ + (size_t)(8 * i_ + srow) * DD),                     \
                (__attribute__((address_space(3))) void*)                     \
                    &myxs[(buf) * XREG + i_ * GS],                            \
                16, 0, 0);                                                    \
        }                                                                     \
    }

    STAGE(0, 0);
#pragma unroll 1
    for (int c = 0; c < NCH; ++c) {
        const int buf = c & 1;
        if (c + 1 < NCH) {
            STAGE(buf ^ 1, c + 1);
            // 8 newest (next chunk's DMA) may stay in flight; chunk c landed.
            asm volatile("s_waitcnt vmcnt(8)" ::: "memory");
        } else {
            asm volatile("s_waitcnt vmcnt(0)" ::: "memory");
        }
        const float* xb = &myxs[buf * XREG];
        const float* wc = wk + c * BK;
#pragma unroll 2
        for (int k4 = 0; k4 < BK / 4; ++k4) {
            float4 xv[8], wv[8];
#pragma unroll
            for (int j = 0; j < 8; ++j)   // 8 distinct bank-quads via XOR group
                xv[j] = *(const float4*)&xb[(j ^ ty) * GS + ty * BK + 4 * k4];
#pragma unroll
            for (int h = 0; h < 8; ++h)   // global b128, L1-hit, 8 independent
                wv[h] = *(const float4*)&wc[woff[h] + 4 * k4];
#pragma unroll
            for (int j = 0; j < 8; ++j)
#pragma unroll
                for (int h = 0; h < 8; ++h) {
                    acc[j][h] += xv[j].x * wv[h].x;
                    acc[j][h] += xv[j].y * wv[h].y;
                    acc[j][h] += xv[j].z * wv[h].z;
                    acc[j][h] += xv[j].w * wv[h].w;
                }
        }
    }

    // ---- per-wave 64x64 partial -> LDS (padded stride: 2-way writes, free) ----
    float* pw = &part[wvu * 64 * PSTR];
#pragma unroll
    for (int j = 0; j < 8; ++j) {
        const int tok = 8 * (j ^ ty) + ty;
#pragma unroll
        for (int h = 0; h < 8; ++h)
            pw[tok * PSTR + 8 * (h ^ tx) + tx] = acc[j][h];
    }
    __syncthreads();

    // ---- reduce 4 wave-partials + bias, top-2 + softmax (wave 0) ----
    if (tid < 64) {
        const int tok = tid;
        float s[EE];
#pragma unroll
        for (int q = 0; q < 16; ++q) {
            const float4 v = *(const float4*)&part[tok * PSTR + 4 * q];
            s[4 * q + 0] = v.x; s[4 * q + 1] = v.y;
            s[4 * q + 2] = v.z; s[4 * q + 3] = v.w;
        }
#pragma unroll
        for (int w = 1; w < NW; ++w)
#pragma unroll
            for (int q = 0; q < 16; ++q) {
                const float4 v = *(const float4*)&part[(w * 64 + tok) * PSTR + 4 * q];
                s[4 * q + 0] += v.x; s[4 * q + 1] += v.y;
                s[4 * q + 2] += v.z; s[4 * q + 3] += v.w;
            }
        float v1 = -INFINITY, v2 = -INFINITY;
        int   i1 = 0, i2 = 0;
#pragma unroll
        for (int e = 0; e < EE; ++e) {   // unrolled: keeps s[] in registers
            const float v = s[e] + bias_g[e];
            if (v > v1) { v2 = v1; i2 = i1; v1 = v; i1 = e; }
            else if (v > v2) { v2 = v; i2 = e; }
        }
        const float ed  = expf(v2 - v1);
        const float inv = 1.f / (1.f + ed);
        const int gt = tBase + tok;
        out[gt * 2 + 0] = inv;
        out[gt * 2 + 1] = ed * inv;
        float* oidx = out + (size_t)2 * n_tokens;
        oidx[gt * 2 + 0] = (float)i1;
        oidx[gt * 2 + 1] = (float)i2;
    }
}

extern "C" void kernel_launch(void* const* d_in, const int* in_sizes, int n_in,
                              void* d_out, int out_size, void* d_ws, size_t ws_size,
                              hipStream_t stream) {
    const float* x = (const float*)d_in[0];
    const float* W = (const float*)d_in[1];
    const float* b = (const float*)d_in[2];
    float* out = (float*)d_out;

    const int n_tokens = in_sizes[0] / DD;  // 16384
    const int n_blocks = n_tokens / 64;     // 256 -> 1 block/CU

    const size_t need = (size_t)EE * WPS * sizeof(float);  // 532 KB
    if (ws_size >= need) {
        float* Wp = (float*)d_ws;
        wprep_kernel<<<EE, 256, 0, stream>>>(W, Wp);
        router_kernel<<<n_blocks, TPB, 0, stream>>>(x, Wp, WPS, b, out, n_tokens);
    } else {
        router_kernel<<<n_blocks, TPB, 0, stream>>>(x, W, DD, b, out, n_tokens);
    }
}